// Round 1
// baseline (1081.143 us; speedup 1.0000x reference)
//
#include <hip/hip_runtime.h>

#define N_NODES   100000
#define N_EDGES   3200000
#define IN_CH     128
#define NUM_GRAPHS 1000

// ---------------------------------------------------------------------------
// K1: t1 = x @ W1_nbr ; r1 = x @ W1_root + b1       (128 -> 16 each)
// block = 256 threads, 8 nodes/block. Combined weight tile in LDS:
// cols 0..15 = nbr, 16..31 = root  -> no divergence in the K-loop.
// ---------------------------------------------------------------------------
__global__ __launch_bounds__(256) void k_transform1(
    const float* __restrict__ x,
    const float* __restrict__ W1n, const float* __restrict__ W1r,
    const float* __restrict__ b1,
    float* __restrict__ t1, float* __restrict__ r1)
{
    __shared__ float sW[IN_CH * 32];   // [k][c]  c<16: nbr, c>=16: root
    __shared__ float sx[8 * IN_CH];

    for (int i = threadIdx.x; i < IN_CH * 32; i += 256) {
        int k = i >> 5, c = i & 31;
        sW[i] = (c < 16) ? W1n[k * 16 + c] : W1r[k * 16 + (c - 16)];
    }
    int node0 = blockIdx.x * 8;
    // 8 rows x 128 floats = 256 float4 loads, one per thread, coalesced
    ((float4*)sx)[threadIdx.x] = ((const float4*)(x + (long)node0 * IN_CH))[threadIdx.x];
    __syncthreads();

    int c  = threadIdx.x & 31;
    int nl = threadIdx.x >> 5;
    const float* xr = &sx[nl * IN_CH];
    float acc = 0.f;
#pragma unroll 8
    for (int k = 0; k < IN_CH; ++k) acc += xr[k] * sW[k * 32 + c];

    int node = node0 + nl;
    if (c < 16) t1[node * 16 + c] = acc;
    else        r1[node * 16 + (c - 16)] = acc + b1[c - 16];
}

// ---------------------------------------------------------------------------
// K2: edge scatter, 16 channels.  thread = (edge, channel)
// agg[dst*16+c] += t[src*16+c]
// ---------------------------------------------------------------------------
__global__ __launch_bounds__(256) void k_scatter16(
    const int* __restrict__ ei, const float* __restrict__ t,
    float* __restrict__ agg)
{
    int tid = blockIdx.x * 256 + threadIdx.x;
    if (tid >= N_EDGES * 16) return;
    int e = tid >> 4, c = tid & 15;
    int src = ei[e];
    int dst = ei[N_EDGES + e];
    atomicAdd(&agg[dst * 16 + c], t[src * 16 + c]);
}

// ---------------------------------------------------------------------------
// K4/K6: edge scatter, 32 channels.
// ---------------------------------------------------------------------------
__global__ __launch_bounds__(256) void k_scatter32(
    const int* __restrict__ ei, const float* __restrict__ t,
    float* __restrict__ agg)
{
    int tid = blockIdx.x * 256 + threadIdx.x;
    if (tid >= N_EDGES * 32) return;
    int e = tid >> 5, c = tid & 31;
    int src = ei[e];
    int dst = ei[N_EDGES + e];
    atomicAdd(&agg[dst * 32 + c], t[src * 32 + c]);
}

// ---------------------------------------------------------------------------
// K3: h1 = relu(r1 + agg1); t2 = h1 @ W2_nbr; r2 = h1 @ W2_root + b2
// 16 -> 32 each. block = 256 = 4 nodes x 64 channels (c<32 nbr, c>=32 root).
// ---------------------------------------------------------------------------
__global__ __launch_bounds__(256) void k_combine1_transform2(
    const float* __restrict__ r1, const float* __restrict__ agg1,
    const float* __restrict__ W2n, const float* __restrict__ W2r,
    const float* __restrict__ b2,
    float* __restrict__ t2, float* __restrict__ r2)
{
    __shared__ float sW[16 * 64];   // [k][c]
    __shared__ float sh[4 * 16];

    for (int i = threadIdx.x; i < 16 * 64; i += 256) {
        int k = i >> 6, c = i & 63;
        sW[i] = (c < 32) ? W2n[k * 32 + c] : W2r[k * 32 + (c - 32)];
    }
    int node0 = blockIdx.x * 4;
    if (threadIdx.x < 64) {
        int idx = node0 * 16 + threadIdx.x;   // 4 nodes x 16 ch contiguous
        float v = r1[idx] + agg1[idx];
        sh[threadIdx.x] = v > 0.f ? v : 0.f;
    }
    __syncthreads();

    int c  = threadIdx.x & 63;
    int nl = threadIdx.x >> 6;
    const float* hr = &sh[nl * 16];
    float acc = 0.f;
#pragma unroll
    for (int k = 0; k < 16; ++k) acc += hr[k] * sW[k * 64 + c];

    int node = node0 + nl;
    if (c < 32) t2[node * 32 + c] = acc;
    else        r2[node * 32 + (c - 32)] = acc + b2[c - 32];
}

// ---------------------------------------------------------------------------
// K5: h2 = relu(r2 + agg2); t3 = h2 @ W3_nbr; r3 = h2 @ W3_root + b3
// 32 -> 32 each. block = 256 = 4 nodes x 64 channels.
// ---------------------------------------------------------------------------
__global__ __launch_bounds__(256) void k_combine2_transform3(
    const float* __restrict__ r2, const float* __restrict__ agg2,
    const float* __restrict__ W3n, const float* __restrict__ W3r,
    const float* __restrict__ b3,
    float* __restrict__ t3, float* __restrict__ r3)
{
    __shared__ float sW[32 * 64];
    __shared__ float sh[4 * 32];

    for (int i = threadIdx.x; i < 32 * 64; i += 256) {
        int k = i >> 6, c = i & 63;
        sW[i] = (c < 32) ? W3n[k * 32 + c] : W3r[k * 32 + (c - 32)];
    }
    int node0 = blockIdx.x * 4;
    {
        int idx = node0 * 32 + threadIdx.x;   // 4 nodes x 32 ch = 128 vals
        if (threadIdx.x < 128) {
            float v = r2[idx] + agg2[idx];
            sh[threadIdx.x] = v > 0.f ? v : 0.f;
        }
    }
    __syncthreads();

    int c  = threadIdx.x & 63;
    int nl = threadIdx.x >> 6;
    const float* hr = &sh[nl * 32];
    float acc = 0.f;
#pragma unroll
    for (int k = 0; k < 32; ++k) acc += hr[k] * sW[k * 64 + c];

    int node = node0 + nl;
    if (c < 32) t3[node * 32 + c] = acc;
    else        r3[node * 32 + (c - 32)] = acc + b3[c - 32];
}

// ---------------------------------------------------------------------------
// K7: h3 = relu(r3 + agg3); pooled[batch[n]] += h3[n]
// ---------------------------------------------------------------------------
__global__ __launch_bounds__(256) void k_combine3_pool(
    const float* __restrict__ r3, const float* __restrict__ agg3,
    const int* __restrict__ batch, float* __restrict__ pooled)
{
    int tid = blockIdx.x * 256 + threadIdx.x;
    if (tid >= N_NODES * 32) return;
    int n = tid >> 5, c = tid & 31;
    float v = r3[tid] + agg3[tid];
    v = v > 0.f ? v : 0.f;
    atomicAdd(&pooled[batch[n] * 32 + c], v);
}

// ---------------------------------------------------------------------------
// K8: out = pooled @ Wlin + blin   (1000x32 @ 32x64)
// ---------------------------------------------------------------------------
__global__ __launch_bounds__(64) void k_final(
    const float* __restrict__ pooled, const float* __restrict__ Wlin,
    const float* __restrict__ blin, float* __restrict__ out)
{
    int g = blockIdx.x;
    int o = threadIdx.x;
    float acc = blin[o];
#pragma unroll
    for (int k = 0; k < 32; ++k) acc += pooled[g * 32 + k] * Wlin[k * 64 + o];
    out[g * 64 + o] = acc;
}

extern "C" void kernel_launch(void* const* d_in, const int* in_sizes, int n_in,
                              void* d_out, int out_size, void* d_ws, size_t ws_size,
                              hipStream_t stream) {
    const float* x     = (const float*)d_in[0];
    const int*   ei    = (const int*)d_in[1];     // [2, E] int32
    const int*   batch = (const int*)d_in[2];
    const float* W1r   = (const float*)d_in[3];
    const float* W1n   = (const float*)d_in[4];
    const float* b1    = (const float*)d_in[5];
    const float* W2r   = (const float*)d_in[6];
    const float* W2n   = (const float*)d_in[7];
    const float* b2    = (const float*)d_in[8];
    const float* W3r   = (const float*)d_in[9];
    const float* W3n   = (const float*)d_in[10];
    const float* b3    = (const float*)d_in[11];
    const float* Wlin  = (const float*)d_in[12];
    const float* blin  = (const float*)d_in[13];
    float* out = (float*)d_out;

    // Workspace layout (floats). Zeroed region first (one memset):
    //   agg1[1.6M] agg2[3.2M] agg3[3.2M] pooled[32K]  -> 8.032M floats
    // then t1[1.6M] r1[1.6M] t2[3.2M] r2[3.2M]
    // t3 aliases (t1,r1) [3.2M dead by K5]; r3 aliases t2 [dead by K5].
    float* ws    = (float*)d_ws;
    float* agg1  = ws;
    float* agg2  = agg1 + (size_t)N_NODES * 16;
    float* agg3  = agg2 + (size_t)N_NODES * 32;
    float* pooled= agg3 + (size_t)N_NODES * 32;
    float* t1    = pooled + (size_t)NUM_GRAPHS * 32;
    float* r1    = t1 + (size_t)N_NODES * 16;
    float* t2    = r1 + (size_t)N_NODES * 16;
    float* r2    = t2 + (size_t)N_NODES * 32;
    float* t3    = t1;   // alias
    float* r3    = t2;   // alias

    size_t zero_floats = (size_t)N_NODES * 16 + (size_t)N_NODES * 32 * 2
                       + (size_t)NUM_GRAPHS * 32;
    hipMemsetAsync(agg1, 0, zero_floats * sizeof(float), stream);

    k_transform1<<<N_NODES / 8, 256, 0, stream>>>(x, W1n, W1r, b1, t1, r1);
    k_scatter16<<<(N_EDGES * 16 + 255) / 256, 256, 0, stream>>>(ei, t1, agg1);
    k_combine1_transform2<<<N_NODES / 4, 256, 0, stream>>>(r1, agg1, W2n, W2r, b2, t2, r2);
    k_scatter32<<<(N_EDGES * 32 + 255) / 256, 256, 0, stream>>>(ei, t2, agg2);
    k_combine2_transform3<<<N_NODES / 4, 256, 0, stream>>>(r2, agg2, W3n, W3r, b3, t3, r3);
    k_scatter32<<<(N_EDGES * 32 + 255) / 256, 256, 0, stream>>>(ei, t3, agg3);
    k_combine3_pool<<<(N_NODES * 32 + 255) / 256, 256, 0, stream>>>(r3, agg3, batch, pooled);
    k_final<<<NUM_GRAPHS, 64, 0, stream>>>(pooled, Wlin, blin, out);
}

// Round 2
// 857.292 us; speedup vs baseline: 1.2611x; 1.2611x over previous
//
#include <hip/hip_runtime.h>

#define N_NODES   100000
#define N_EDGES   3200000
#define IN_CH     128
#define NUM_GRAPHS 1000
#define NBLK_SCAN 391   // ceil(100000/256)

// ---------------------------------------------------------------------------
// CSR build: histogram -> hierarchical exclusive scan -> fill
// ---------------------------------------------------------------------------
__global__ __launch_bounds__(256) void k_hist(const int* __restrict__ ei,
                                              int* __restrict__ deg)
{
    int e = blockIdx.x * 256 + threadIdx.x;
    if (e >= N_EDGES) return;
    atomicAdd(&deg[ei[N_EDGES + e]], 1);
}

__global__ __launch_bounds__(256) void k_blocksum(const int* __restrict__ deg,
                                                  int* __restrict__ bsum)
{
    int i = blockIdx.x * 256 + threadIdx.x;
    int v = (i < N_NODES) ? deg[i] : 0;
#pragma unroll
    for (int off = 32; off; off >>= 1) v += __shfl_down(v, off, 64);
    __shared__ int s[4];
    if ((threadIdx.x & 63) == 0) s[threadIdx.x >> 6] = v;
    __syncthreads();
    if (threadIdx.x == 0) bsum[blockIdx.x] = s[0] + s[1] + s[2] + s[3];
}

__global__ __launch_bounds__(512) void k_scan_bsum(int* __restrict__ bsum)
{
    __shared__ int sh[512];
    int tid = threadIdx.x;
    int v = (tid < NBLK_SCAN) ? bsum[tid] : 0;
    sh[tid] = v;
    __syncthreads();
    for (int off = 1; off < 512; off <<= 1) {
        int t = (tid >= off) ? sh[tid - off] : 0;
        __syncthreads();
        sh[tid] += t;
        __syncthreads();
    }
    if (tid < NBLK_SCAN) bsum[tid] = sh[tid] - v;   // exclusive
}

__global__ __launch_bounds__(256) void k_scan_deg(const int* __restrict__ deg,
                                                  const int* __restrict__ bsum,
                                                  int* __restrict__ rowptr)
{
    __shared__ int sh[256];
    int i = blockIdx.x * 256 + threadIdx.x;
    int tid = threadIdx.x;
    int v = (i < N_NODES) ? deg[i] : 0;
    sh[tid] = v;
    __syncthreads();
    for (int off = 1; off < 256; off <<= 1) {
        int t = (tid >= off) ? sh[tid - off] : 0;
        __syncthreads();
        sh[tid] += t;
        __syncthreads();
    }
    int ex = bsum[blockIdx.x] + sh[tid] - v;        // exclusive
    if (i < N_NODES) rowptr[i] = ex;
    if (i == N_NODES - 1) rowptr[N_NODES] = ex + v;
}

__global__ __launch_bounds__(256) void k_fill(const int* __restrict__ ei,
                                              const int* __restrict__ rowptr,
                                              int* __restrict__ cursor,
                                              int* __restrict__ csr)
{
    int e = blockIdx.x * 256 + threadIdx.x;
    if (e >= N_EDGES) return;
    int src = ei[e];
    int dst = ei[N_EDGES + e];
    int pos = atomicAdd(&cursor[dst], 1);
    csr[rowptr[dst] + pos] = src;
}

// ---------------------------------------------------------------------------
// K1: t1 = x @ W1_nbr ; r1 = x @ W1_root + b1       (128 -> 16 each)
// ---------------------------------------------------------------------------
__global__ __launch_bounds__(256) void k_transform1(
    const float* __restrict__ x,
    const float* __restrict__ W1n, const float* __restrict__ W1r,
    const float* __restrict__ b1,
    float* __restrict__ t1, float* __restrict__ r1)
{
    __shared__ float sW[IN_CH * 32];   // [k][c]  c<16: nbr, c>=16: root
    __shared__ float sx[8 * IN_CH];

    for (int i = threadIdx.x; i < IN_CH * 32; i += 256) {
        int k = i >> 5, c = i & 31;
        sW[i] = (c < 16) ? W1n[k * 16 + c] : W1r[k * 16 + (c - 16)];
    }
    int node0 = blockIdx.x * 8;
    ((float4*)sx)[threadIdx.x] = ((const float4*)(x + (long)node0 * IN_CH))[threadIdx.x];
    __syncthreads();

    int c  = threadIdx.x & 31;
    int nl = threadIdx.x >> 5;
    const float* xr = &sx[nl * IN_CH];
    float acc = 0.f;
#pragma unroll 8
    for (int k = 0; k < IN_CH; ++k) acc += xr[k] * sW[k * 32 + c];

    int node = node0 + nl;
    if (c < 16) t1[node * 16 + c] = acc;
    else        r1[node * 16 + (c - 16)] = acc + b1[c - 16];
}

// ---------------------------------------------------------------------------
// Gather (CSR): agg[n,c] = sum over in-edges of t[src,c].  No atomics.
// ---------------------------------------------------------------------------
__global__ __launch_bounds__(256) void k_gather16(
    const int* __restrict__ rowptr, const int* __restrict__ csr,
    const float* __restrict__ t, float* __restrict__ agg)
{
    int tid = blockIdx.x * 256 + threadIdx.x;
    int n = tid >> 4, c = tid & 15;
    if (n >= N_NODES) return;
    int j = rowptr[n], end = rowptr[n + 1];
    float acc0 = 0.f, acc1 = 0.f;
    for (; j + 1 < end; j += 2) {
        int sA = csr[j], sB = csr[j + 1];
        acc0 += t[sA * 16 + c];
        acc1 += t[sB * 16 + c];
    }
    if (j < end) acc0 += t[csr[j] * 16 + c];
    agg[n * 16 + c] = acc0 + acc1;
}

__global__ __launch_bounds__(256) void k_gather32(
    const int* __restrict__ rowptr, const int* __restrict__ csr,
    const float* __restrict__ t, float* __restrict__ agg)
{
    int tid = blockIdx.x * 256 + threadIdx.x;
    int n = tid >> 5, c = tid & 31;
    if (n >= N_NODES) return;
    int j = rowptr[n], end = rowptr[n + 1];
    float acc0 = 0.f, acc1 = 0.f;
    for (; j + 1 < end; j += 2) {
        int sA = csr[j], sB = csr[j + 1];
        acc0 += t[sA * 32 + c];
        acc1 += t[sB * 32 + c];
    }
    if (j < end) acc0 += t[csr[j] * 32 + c];
    agg[n * 32 + c] = acc0 + acc1;
}

// ---------------------------------------------------------------------------
// K3: h1 = relu(r1 + agg); t2 = h1 @ W2_nbr; r2 = h1 @ W2_root + b2
// ---------------------------------------------------------------------------
__global__ __launch_bounds__(256) void k_combine1_transform2(
    const float* __restrict__ r1, const float* __restrict__ agg1,
    const float* __restrict__ W2n, const float* __restrict__ W2r,
    const float* __restrict__ b2,
    float* __restrict__ t2, float* __restrict__ r2)
{
    __shared__ float sW[16 * 64];   // [k][c]
    __shared__ float sh[4 * 16];

    for (int i = threadIdx.x; i < 16 * 64; i += 256) {
        int k = i >> 6, c = i & 63;
        sW[i] = (c < 32) ? W2n[k * 32 + c] : W2r[k * 32 + (c - 32)];
    }
    int node0 = blockIdx.x * 4;
    if (threadIdx.x < 64) {
        int idx = node0 * 16 + threadIdx.x;
        float v = r1[idx] + agg1[idx];
        sh[threadIdx.x] = v > 0.f ? v : 0.f;
    }
    __syncthreads();

    int c  = threadIdx.x & 63;
    int nl = threadIdx.x >> 6;
    const float* hr = &sh[nl * 16];
    float acc = 0.f;
#pragma unroll
    for (int k = 0; k < 16; ++k) acc += hr[k] * sW[k * 64 + c];

    int node = node0 + nl;
    if (c < 32) t2[node * 32 + c] = acc;
    else        r2[node * 32 + (c - 32)] = acc + b2[c - 32];
}

// ---------------------------------------------------------------------------
// K5: h2 = relu(r2 + agg); t3 = h2 @ W3_nbr; r3 = h2 @ W3_root + b3
// NOTE: t3/r3 may alias t2/r2 — block reads its own slice to LDS, barrier,
// then overwrites only its own slice. Safe in-place.
// ---------------------------------------------------------------------------
__global__ __launch_bounds__(256) void k_combine2_transform3(
    const float* __restrict__ r2, const float* __restrict__ agg2,
    const float* __restrict__ W3n, const float* __restrict__ W3r,
    const float* __restrict__ b3,
    float* __restrict__ t3, float* __restrict__ r3)
{
    __shared__ float sW[32 * 64];
    __shared__ float sh[4 * 32];

    for (int i = threadIdx.x; i < 32 * 64; i += 256) {
        int k = i >> 6, c = i & 63;
        sW[i] = (c < 32) ? W3n[k * 32 + c] : W3r[k * 32 + (c - 32)];
    }
    int node0 = blockIdx.x * 4;
    if (threadIdx.x < 128) {
        int idx = node0 * 32 + threadIdx.x;
        float v = r2[idx] + agg2[idx];
        sh[threadIdx.x] = v > 0.f ? v : 0.f;
    }
    __syncthreads();

    int c  = threadIdx.x & 63;
    int nl = threadIdx.x >> 6;
    const float* hr = &sh[nl * 32];
    float acc = 0.f;
#pragma unroll
    for (int k = 0; k < 32; ++k) acc += hr[k] * sW[k * 64 + c];

    int node = node0 + nl;
    if (c < 32) t3[node * 32 + c] = acc;
    else        r3[node * 32 + (c - 32)] = acc + b3[c - 32];
}

// ---------------------------------------------------------------------------
// K7: h3 = relu(r3 + agg); pooled[batch[n]] += h3[n]
// ---------------------------------------------------------------------------
__global__ __launch_bounds__(256) void k_combine3_pool(
    const float* __restrict__ r3, const float* __restrict__ agg3,
    const int* __restrict__ batch, float* __restrict__ pooled)
{
    int tid = blockIdx.x * 256 + threadIdx.x;
    if (tid >= N_NODES * 32) return;
    int n = tid >> 5, c = tid & 31;
    float v = r3[tid] + agg3[tid];
    v = v > 0.f ? v : 0.f;
    atomicAdd(&pooled[batch[n] * 32 + c], v);
}

// ---------------------------------------------------------------------------
// K8: out = pooled @ Wlin + blin   (1000x32 @ 32x64)
// ---------------------------------------------------------------------------
__global__ __launch_bounds__(64) void k_final(
    const float* __restrict__ pooled, const float* __restrict__ Wlin,
    const float* __restrict__ blin, float* __restrict__ out)
{
    int g = blockIdx.x;
    int o = threadIdx.x;
    float acc = blin[o];
#pragma unroll
    for (int k = 0; k < 32; ++k) acc += pooled[g * 32 + k] * Wlin[k * 64 + o];
    out[g * 64 + o] = acc;
}

extern "C" void kernel_launch(void* const* d_in, const int* in_sizes, int n_in,
                              void* d_out, int out_size, void* d_ws, size_t ws_size,
                              hipStream_t stream) {
    const float* x     = (const float*)d_in[0];
    const int*   ei    = (const int*)d_in[1];
    const int*   batch = (const int*)d_in[2];
    const float* W1r   = (const float*)d_in[3];
    const float* W1n   = (const float*)d_in[4];
    const float* b1    = (const float*)d_in[5];
    const float* W2r   = (const float*)d_in[6];
    const float* W2n   = (const float*)d_in[7];
    const float* b2    = (const float*)d_in[8];
    const float* W3r   = (const float*)d_in[9];
    const float* W3n   = (const float*)d_in[10];
    const float* b3    = (const float*)d_in[11];
    const float* Wlin  = (const float*)d_in[12];
    const float* blin  = (const float*)d_in[13];
    float* out = (float*)d_out;

    // ---- workspace layout --------------------------------------------------
    // zero region: deg[100k] cursor[100k] pooled[32k floats]  (one memset)
    // then: bsum[391(pad 512)] rowptr[100k+1] csr[3.2M]
    // floats: t1[1.6M] r1[1.6M] t2[3.2M] r2[3.2M] agg[3.2M]
    // t3/r3 alias t2/r2 (in-place, barrier-protected). Total ~= 66 MB.
    char* wsb = (char*)d_ws;
    int*   deg    = (int*)wsb;
    int*   cursor = deg + N_NODES;
    float* pooled = (float*)(cursor + N_NODES);
    int*   bsum   = (int*)(pooled + NUM_GRAPHS * 32);
    int*   rowptr = bsum + 512;
    int*   csr    = rowptr + (N_NODES + 1);
    float* t1     = (float*)(csr + N_EDGES);
    float* r1     = t1 + (size_t)N_NODES * 16;
    float* t2     = r1 + (size_t)N_NODES * 16;
    float* r2     = t2 + (size_t)N_NODES * 32;
    float* agg    = r2 + (size_t)N_NODES * 32;
    float* t3     = t2;   // in-place
    float* r3     = r2;   // in-place

    size_t zero_bytes = ((size_t)N_NODES * 2 + NUM_GRAPHS * 32) * 4;
    hipMemsetAsync(deg, 0, zero_bytes, stream);

    // CSR build
    k_hist     <<<(N_EDGES + 255) / 256, 256, 0, stream>>>(ei, deg);
    k_blocksum <<<NBLK_SCAN, 256, 0, stream>>>(deg, bsum);
    k_scan_bsum<<<1, 512, 0, stream>>>(bsum);
    k_scan_deg <<<NBLK_SCAN, 256, 0, stream>>>(deg, bsum, rowptr);
    k_fill     <<<(N_EDGES + 255) / 256, 256, 0, stream>>>(ei, rowptr, cursor, csr);

    // Layer pipeline
    k_transform1<<<N_NODES / 8, 256, 0, stream>>>(x, W1n, W1r, b1, t1, r1);
    k_gather16  <<<N_NODES * 16 / 256, 256, 0, stream>>>(rowptr, csr, t1, agg);
    k_combine1_transform2<<<N_NODES / 4, 256, 0, stream>>>(r1, agg, W2n, W2r, b2, t2, r2);
    k_gather32  <<<N_NODES * 32 / 256, 256, 0, stream>>>(rowptr, csr, t2, agg);
    k_combine2_transform3<<<N_NODES / 4, 256, 0, stream>>>(r2, agg, W3n, W3r, b3, t3, r3);
    k_gather32  <<<N_NODES * 32 / 256, 256, 0, stream>>>(rowptr, csr, t3, agg);
    k_combine3_pool<<<N_NODES * 32 / 256, 256, 0, stream>>>(r3, agg, batch, pooled);
    k_final     <<<NUM_GRAPHS, 64, 0, stream>>>(pooled, Wlin, blin, out);
}

// Round 3
// 581.074 us; speedup vs baseline: 1.8606x; 1.4754x over previous
//
#include <hip/hip_runtime.h>

#define N_NODES   100000
#define N_EDGES   3200000
#define IN_CH     128
#define NUM_GRAPHS 1000
#define NB        391      // ceil(100000/256) buckets, 256 nodes each
#define CHUNK     4096     // edges per block in binning passes
#define NBLK_BIN  782      // ceil(3200000/4096)
#define CAP       16384    // LDS edge-staging capacity in k_build_csr

// ---------------------------------------------------------------------------
// Phase A: per-bucket edge counts (bucket = dst >> 8)
// ---------------------------------------------------------------------------
__global__ __launch_bounds__(256) void k_count_buckets(const int* __restrict__ ei,
                                                       int* __restrict__ gcount)
{
    __shared__ int h[NB];
    for (int i = threadIdx.x; i < NB; i += 256) h[i] = 0;
    __syncthreads();
    int base = blockIdx.x * CHUNK;
    int end = min(base + CHUNK, N_EDGES);
    for (int e = base + threadIdx.x; e < end; e += 256)
        atomicAdd(&h[ei[N_EDGES + e] >> 8], 1);
    __syncthreads();
    for (int i = threadIdx.x; i < NB; i += 256)
        if (h[i]) atomicAdd(&gcount[i], h[i]);
}

// ---------------------------------------------------------------------------
// Phase B: exclusive scan of 391 bucket counts -> boff; cursor = boff copy
// ---------------------------------------------------------------------------
__global__ __launch_bounds__(512) void k_scan_buckets(const int* __restrict__ gcount,
                                                      int* __restrict__ boff,
                                                      int* __restrict__ cursor)
{
    __shared__ int sh[512];
    int tid = threadIdx.x;
    int v = (tid < NB) ? gcount[tid] : 0;
    sh[tid] = v;
    __syncthreads();
    for (int off = 1; off < 512; off <<= 1) {
        int t = (tid >= off) ? sh[tid - off] : 0;
        __syncthreads();
        sh[tid] += t;
        __syncthreads();
    }
    if (tid < NB) {
        int ex = sh[tid] - v;
        boff[tid] = ex;
        cursor[tid] = ex;
    }
}

// ---------------------------------------------------------------------------
// Phase C: scatter packed (src | dst_local<<17) into per-bucket regions.
// Each block reserves per-bucket ranges -> writes land in small dense windows.
// ---------------------------------------------------------------------------
__global__ __launch_bounds__(256) void k_scatter_pairs(const int* __restrict__ ei,
                                                       int* __restrict__ cursor,
                                                       int* __restrict__ pairbuf)
{
    __shared__ int h[NB];
    __shared__ int lbase[NB];
    for (int i = threadIdx.x; i < NB; i += 256) h[i] = 0;
    __syncthreads();
    int base = blockIdx.x * CHUNK;
    int end = min(base + CHUNK, N_EDGES);
    for (int e = base + threadIdx.x; e < end; e += 256)
        atomicAdd(&h[ei[N_EDGES + e] >> 8], 1);
    __syncthreads();
    for (int i = threadIdx.x; i < NB; i += 256) {
        int c = h[i];
        lbase[i] = c ? atomicAdd(&cursor[i], c) : 0;
        h[i] = 0;   // reuse as local cursor
    }
    __syncthreads();
    for (int e = base + threadIdx.x; e < end; e += 256) {
        int src = ei[e];
        int dst = ei[N_EDGES + e];
        int b = dst >> 8;
        int off = atomicAdd(&h[b], 1);
        pairbuf[lbase[b] + off] = src | ((dst & 255) << 17);
    }
}

// ---------------------------------------------------------------------------
// Phase D: one block per bucket. Stage edges in LDS, count per node, LDS scan
// -> rowptr (bucket base = boff[b], so NO global node scan needed), then
// scatter src into the bucket's contiguous csr window (L2-resident).
// ---------------------------------------------------------------------------
__global__ __launch_bounds__(256) void k_build_csr(const int* __restrict__ gcount,
                                                   const int* __restrict__ boff,
                                                   const int* __restrict__ pairbuf,
                                                   int* __restrict__ rowptr,
                                                   int* __restrict__ csr)
{
    __shared__ int cnt[256];
    __shared__ int scanv[256];
    __shared__ int ebuf[CAP];
    int b = blockIdx.x;
    int node0 = b << 8;
    int cntE = gcount[b];
    int base = boff[b];
    int tid = threadIdx.x;
    cnt[tid] = 0;
    __syncthreads();
    bool inLds = (cntE <= CAP);
    for (int i = tid; i < cntE; i += 256) {
        int p = pairbuf[base + i];
        if (inLds) ebuf[i] = p;
        atomicAdd(&cnt[(p >> 17) & 255], 1);
    }
    __syncthreads();
    int v = cnt[tid];
    scanv[tid] = v;
    __syncthreads();
    for (int off = 1; off < 256; off <<= 1) {
        int t = (tid >= off) ? scanv[tid - off] : 0;
        __syncthreads();
        scanv[tid] += t;
        __syncthreads();
    }
    int ex = scanv[tid] - v;           // exclusive within bucket
    int node = node0 + tid;
    if (node < N_NODES) rowptr[node] = base + ex;
    if (b == NB - 1 && tid == 0) rowptr[N_NODES] = N_EDGES;
    __syncthreads();
    cnt[tid] = ex;                     // local cursor
    __syncthreads();
    for (int i = tid; i < cntE; i += 256) {
        int p = inLds ? ebuf[i] : pairbuf[base + i];
        int pos = atomicAdd(&cnt[(p >> 17) & 255], 1);
        csr[base + pos] = p & 0x1FFFF;
    }
}

// ---------------------------------------------------------------------------
// K1: t1 = x @ W1_nbr ; r1 = x @ W1_root + b1       (128 -> 16 each)
// ---------------------------------------------------------------------------
__global__ __launch_bounds__(256) void k_transform1(
    const float* __restrict__ x,
    const float* __restrict__ W1n, const float* __restrict__ W1r,
    const float* __restrict__ b1,
    float* __restrict__ t1, float* __restrict__ r1)
{
    __shared__ float sW[IN_CH * 32];   // [k][c]  c<16: nbr, c>=16: root
    __shared__ float sx[8 * IN_CH];

    for (int i = threadIdx.x; i < IN_CH * 32; i += 256) {
        int k = i >> 5, c = i & 31;
        sW[i] = (c < 16) ? W1n[k * 16 + c] : W1r[k * 16 + (c - 16)];
    }
    int node0 = blockIdx.x * 8;
    ((float4*)sx)[threadIdx.x] = ((const float4*)(x + (long)node0 * IN_CH))[threadIdx.x];
    __syncthreads();

    int c  = threadIdx.x & 31;
    int nl = threadIdx.x >> 5;
    const float* xr = &sx[nl * IN_CH];
    float acc = 0.f;
#pragma unroll 8
    for (int k = 0; k < IN_CH; ++k) acc += xr[k] * sW[k * 32 + c];

    int node = node0 + nl;
    if (c < 16) t1[node * 16 + c] = acc;
    else        r1[node * 16 + (c - 16)] = acc + b1[c - 16];
}

// ---------------------------------------------------------------------------
// Gather (CSR): agg[n,c] = sum over in-edges of t[src,c].  No atomics.
// 4-way unrolled for memory-level parallelism.
// ---------------------------------------------------------------------------
__global__ __launch_bounds__(256) void k_gather16(
    const int* __restrict__ rowptr, const int* __restrict__ csr,
    const float* __restrict__ t, float* __restrict__ agg)
{
    int tid = blockIdx.x * 256 + threadIdx.x;
    int n = tid >> 4, c = tid & 15;
    if (n >= N_NODES) return;
    int j = rowptr[n], end = rowptr[n + 1];
    float a0 = 0.f, a1 = 0.f, a2 = 0.f, a3 = 0.f;
    for (; j + 3 < end; j += 4) {
        int s0 = csr[j], s1 = csr[j + 1], s2 = csr[j + 2], s3 = csr[j + 3];
        a0 += t[s0 * 16 + c];
        a1 += t[s1 * 16 + c];
        a2 += t[s2 * 16 + c];
        a3 += t[s3 * 16 + c];
    }
    for (; j < end; ++j) a0 += t[csr[j] * 16 + c];
    agg[n * 16 + c] = (a0 + a1) + (a2 + a3);
}

__global__ __launch_bounds__(256) void k_gather32(
    const int* __restrict__ rowptr, const int* __restrict__ csr,
    const float* __restrict__ t, float* __restrict__ agg)
{
    int tid = blockIdx.x * 256 + threadIdx.x;
    int n = tid >> 5, c = tid & 31;
    if (n >= N_NODES) return;
    int j = rowptr[n], end = rowptr[n + 1];
    float a0 = 0.f, a1 = 0.f, a2 = 0.f, a3 = 0.f;
    for (; j + 3 < end; j += 4) {
        int s0 = csr[j], s1 = csr[j + 1], s2 = csr[j + 2], s3 = csr[j + 3];
        a0 += t[s0 * 32 + c];
        a1 += t[s1 * 32 + c];
        a2 += t[s2 * 32 + c];
        a3 += t[s3 * 32 + c];
    }
    for (; j < end; ++j) a0 += t[csr[j] * 32 + c];
    agg[n * 32 + c] = (a0 + a1) + (a2 + a3);
}

// ---------------------------------------------------------------------------
// K3: h1 = relu(r1 + agg); t2 = h1 @ W2_nbr; r2 = h1 @ W2_root + b2
// ---------------------------------------------------------------------------
__global__ __launch_bounds__(256) void k_combine1_transform2(
    const float* __restrict__ r1, const float* __restrict__ agg1,
    const float* __restrict__ W2n, const float* __restrict__ W2r,
    const float* __restrict__ b2,
    float* __restrict__ t2, float* __restrict__ r2)
{
    __shared__ float sW[16 * 64];   // [k][c]
    __shared__ float sh[4 * 16];

    for (int i = threadIdx.x; i < 16 * 64; i += 256) {
        int k = i >> 6, c = i & 63;
        sW[i] = (c < 32) ? W2n[k * 32 + c] : W2r[k * 32 + (c - 32)];
    }
    int node0 = blockIdx.x * 4;
    if (threadIdx.x < 64) {
        int idx = node0 * 16 + threadIdx.x;
        float v = r1[idx] + agg1[idx];
        sh[threadIdx.x] = v > 0.f ? v : 0.f;
    }
    __syncthreads();

    int c  = threadIdx.x & 63;
    int nl = threadIdx.x >> 6;
    const float* hr = &sh[nl * 16];
    float acc = 0.f;
#pragma unroll
    for (int k = 0; k < 16; ++k) acc += hr[k] * sW[k * 64 + c];

    int node = node0 + nl;
    if (c < 32) t2[node * 32 + c] = acc;
    else        r2[node * 32 + (c - 32)] = acc + b2[c - 32];
}

// ---------------------------------------------------------------------------
// K5: h2 = relu(r2 + agg); t3 = h2 @ W3_nbr; r3 = h2 @ W3_root + b3
// t3/r3 alias t2/r2 — block reads its slice to LDS, barrier, overwrites.
// ---------------------------------------------------------------------------
__global__ __launch_bounds__(256) void k_combine2_transform3(
    const float* __restrict__ r2, const float* __restrict__ agg2,
    const float* __restrict__ W3n, const float* __restrict__ W3r,
    const float* __restrict__ b3,
    float* __restrict__ t3, float* __restrict__ r3)
{
    __shared__ float sW[32 * 64];
    __shared__ float sh[4 * 32];

    for (int i = threadIdx.x; i < 32 * 64; i += 256) {
        int k = i >> 6, c = i & 63;
        sW[i] = (c < 32) ? W3n[k * 32 + c] : W3r[k * 32 + (c - 32)];
    }
    int node0 = blockIdx.x * 4;
    if (threadIdx.x < 128) {
        int idx = node0 * 32 + threadIdx.x;
        float v = r2[idx] + agg2[idx];
        sh[threadIdx.x] = v > 0.f ? v : 0.f;
    }
    __syncthreads();

    int c  = threadIdx.x & 63;
    int nl = threadIdx.x >> 6;
    const float* hr = &sh[nl * 32];
    float acc = 0.f;
#pragma unroll
    for (int k = 0; k < 32; ++k) acc += hr[k] * sW[k * 64 + c];

    int node = node0 + nl;
    if (c < 32) t3[node * 32 + c] = acc;
    else        r3[node * 32 + (c - 32)] = acc + b3[c - 32];
}

// ---------------------------------------------------------------------------
// K7: h3 = relu(r3 + agg); pooled[batch[n]] += h3[n]
// ---------------------------------------------------------------------------
__global__ __launch_bounds__(256) void k_combine3_pool(
    const float* __restrict__ r3, const float* __restrict__ agg3,
    const int* __restrict__ batch, float* __restrict__ pooled)
{
    int tid = blockIdx.x * 256 + threadIdx.x;
    if (tid >= N_NODES * 32) return;
    int n = tid >> 5, c = tid & 31;
    float v = r3[tid] + agg3[tid];
    v = v > 0.f ? v : 0.f;
    atomicAdd(&pooled[batch[n] * 32 + c], v);
}

// ---------------------------------------------------------------------------
// K8: out = pooled @ Wlin + blin   (1000x32 @ 32x64)
// ---------------------------------------------------------------------------
__global__ __launch_bounds__(64) void k_final(
    const float* __restrict__ pooled, const float* __restrict__ Wlin,
    const float* __restrict__ blin, float* __restrict__ out)
{
    int g = blockIdx.x;
    int o = threadIdx.x;
    float acc = blin[o];
#pragma unroll
    for (int k = 0; k < 32; ++k) acc += pooled[g * 32 + k] * Wlin[k * 64 + o];
    out[g * 64 + o] = acc;
}

extern "C" void kernel_launch(void* const* d_in, const int* in_sizes, int n_in,
                              void* d_out, int out_size, void* d_ws, size_t ws_size,
                              hipStream_t stream) {
    const float* x     = (const float*)d_in[0];
    const int*   ei    = (const int*)d_in[1];
    const int*   batch = (const int*)d_in[2];
    const float* W1r   = (const float*)d_in[3];
    const float* W1n   = (const float*)d_in[4];
    const float* b1    = (const float*)d_in[5];
    const float* W2r   = (const float*)d_in[6];
    const float* W2n   = (const float*)d_in[7];
    const float* b2    = (const float*)d_in[8];
    const float* W3r   = (const float*)d_in[9];
    const float* W3n   = (const float*)d_in[10];
    const float* b3    = (const float*)d_in[11];
    const float* Wlin  = (const float*)d_in[12];
    const float* blin  = (const float*)d_in[13];
    float* out = (float*)d_out;

    // ---- workspace layout (words) -----------------------------------------
    // zero region: gcount[512] + pooled[32000]              (one small memset)
    // boff[512] cursor[512] rowptr[100001] csr[3.2M]
    // pairbuf[3.2M]  -- ALIASES t1[1.6M]+r1[1.6M] (pairbuf dead before K1)
    // t2[3.2M] r2[3.2M] agg[3.2M] floats; t3/r3 alias t2/r2. Total ~64.5 MB.
    int*   gcount = (int*)d_ws;
    float* pooled = (float*)(gcount + 512);
    int*   boff   = (int*)(pooled + NUM_GRAPHS * 32);
    int*   cursor = boff + 512;
    int*   rowptr = cursor + 512;
    int*   csr    = rowptr + (N_NODES + 1);
    int*   pairbuf= csr + N_EDGES;
    float* t1     = (float*)pairbuf;              // alias
    float* r1     = t1 + (size_t)N_NODES * 16;
    float* t2     = (float*)(pairbuf + N_EDGES);
    float* r2     = t2 + (size_t)N_NODES * 32;
    float* agg    = r2 + (size_t)N_NODES * 32;
    float* t3     = t2;   // in-place
    float* r3     = r2;   // in-place

    hipMemsetAsync(gcount, 0, (512 + (size_t)NUM_GRAPHS * 32) * 4, stream);

    // CSR build (bucketed, write-allocate-friendly)
    k_count_buckets<<<NBLK_BIN, 256, 0, stream>>>(ei, gcount);
    k_scan_buckets <<<1, 512, 0, stream>>>(gcount, boff, cursor);
    k_scatter_pairs<<<NBLK_BIN, 256, 0, stream>>>(ei, cursor, pairbuf);
    k_build_csr    <<<NB, 256, 0, stream>>>(gcount, boff, pairbuf, rowptr, csr);

    // Layer pipeline
    k_transform1<<<N_NODES / 8, 256, 0, stream>>>(x, W1n, W1r, b1, t1, r1);
    k_gather16  <<<N_NODES * 16 / 256, 256, 0, stream>>>(rowptr, csr, t1, agg);
    k_combine1_transform2<<<N_NODES / 4, 256, 0, stream>>>(r1, agg, W2n, W2r, b2, t2, r2);
    k_gather32  <<<N_NODES * 32 / 256, 256, 0, stream>>>(rowptr, csr, t2, agg);
    k_combine2_transform3<<<N_NODES / 4, 256, 0, stream>>>(r2, agg, W3n, W3r, b3, t3, r3);
    k_gather32  <<<N_NODES * 32 / 256, 256, 0, stream>>>(rowptr, csr, t3, agg);
    k_combine3_pool<<<N_NODES * 32 / 256, 256, 0, stream>>>(r3, agg, batch, pooled);
    k_final     <<<NUM_GRAPHS, 64, 0, stream>>>(pooled, Wlin, blin, out);
}

// Round 4
// 514.443 us; speedup vs baseline: 2.1016x; 1.1295x over previous
//
#include <hip/hip_runtime.h>
#include <hip/hip_fp16.h>

#define N_NODES   100000
#define N_EDGES   3200000
#define IN_CH     128
#define NUM_GRAPHS 1000
#define NB        391      // ceil(100000/256) buckets, 256 nodes each
#define CHUNK     4096     // edges per block in binning passes
#define NBLK_BIN  782      // ceil(3200000/4096)
#define CAP       16384    // LDS edge-staging capacity in k_build_csr

// ---------------------------------------------------------------------------
// Phase A: per-bucket edge counts (bucket = dst >> 8)
// ---------------------------------------------------------------------------
__global__ __launch_bounds__(256) void k_count_buckets(const int* __restrict__ ei,
                                                       int* __restrict__ gcount)
{
    __shared__ int h[NB];
    for (int i = threadIdx.x; i < NB; i += 256) h[i] = 0;
    __syncthreads();
    int base = blockIdx.x * CHUNK;
    int end = min(base + CHUNK, N_EDGES);
    for (int e = base + threadIdx.x; e < end; e += 256)
        atomicAdd(&h[ei[N_EDGES + e] >> 8], 1);
    __syncthreads();
    for (int i = threadIdx.x; i < NB; i += 256)
        if (h[i]) atomicAdd(&gcount[i], h[i]);
}

// ---------------------------------------------------------------------------
// Phase B: exclusive scan of 391 bucket counts -> boff; cursor = boff copy
// ---------------------------------------------------------------------------
__global__ __launch_bounds__(512) void k_scan_buckets(const int* __restrict__ gcount,
                                                      int* __restrict__ boff,
                                                      int* __restrict__ cursor)
{
    __shared__ int sh[512];
    int tid = threadIdx.x;
    int v = (tid < NB) ? gcount[tid] : 0;
    sh[tid] = v;
    __syncthreads();
    for (int off = 1; off < 512; off <<= 1) {
        int t = (tid >= off) ? sh[tid - off] : 0;
        __syncthreads();
        sh[tid] += t;
        __syncthreads();
    }
    if (tid < NB) {
        int ex = sh[tid] - v;
        boff[tid] = ex;
        cursor[tid] = ex;
    }
}

// ---------------------------------------------------------------------------
// Phase C: scatter packed (src | dst_local<<17) into per-bucket regions.
// ---------------------------------------------------------------------------
__global__ __launch_bounds__(256) void k_scatter_pairs(const int* __restrict__ ei,
                                                       int* __restrict__ cursor,
                                                       int* __restrict__ pairbuf)
{
    __shared__ int h[NB];
    __shared__ int lbase[NB];
    for (int i = threadIdx.x; i < NB; i += 256) h[i] = 0;
    __syncthreads();
    int base = blockIdx.x * CHUNK;
    int end = min(base + CHUNK, N_EDGES);
    for (int e = base + threadIdx.x; e < end; e += 256)
        atomicAdd(&h[ei[N_EDGES + e] >> 8], 1);
    __syncthreads();
    for (int i = threadIdx.x; i < NB; i += 256) {
        int c = h[i];
        lbase[i] = c ? atomicAdd(&cursor[i], c) : 0;
        h[i] = 0;   // reuse as local cursor
    }
    __syncthreads();
    for (int e = base + threadIdx.x; e < end; e += 256) {
        int src = ei[e];
        int dst = ei[N_EDGES + e];
        int b = dst >> 8;
        int off = atomicAdd(&h[b], 1);
        pairbuf[lbase[b] + off] = src | ((dst & 255) << 17);
    }
}

// ---------------------------------------------------------------------------
// Phase D: one block per bucket -> rowptr + csr (bucket window L2-resident).
// ---------------------------------------------------------------------------
__global__ __launch_bounds__(256) void k_build_csr(const int* __restrict__ gcount,
                                                   const int* __restrict__ boff,
                                                   const int* __restrict__ pairbuf,
                                                   int* __restrict__ rowptr,
                                                   int* __restrict__ csr)
{
    __shared__ int cnt[256];
    __shared__ int scanv[256];
    __shared__ int ebuf[CAP];
    int b = blockIdx.x;
    int node0 = b << 8;
    int cntE = gcount[b];
    int base = boff[b];
    int tid = threadIdx.x;
    cnt[tid] = 0;
    __syncthreads();
    bool inLds = (cntE <= CAP);
    for (int i = tid; i < cntE; i += 256) {
        int p = pairbuf[base + i];
        if (inLds) ebuf[i] = p;
        atomicAdd(&cnt[(p >> 17) & 255], 1);
    }
    __syncthreads();
    int v = cnt[tid];
    scanv[tid] = v;
    __syncthreads();
    for (int off = 1; off < 256; off <<= 1) {
        int t = (tid >= off) ? scanv[tid - off] : 0;
        __syncthreads();
        scanv[tid] += t;
        __syncthreads();
    }
    int ex = scanv[tid] - v;           // exclusive within bucket
    int node = node0 + tid;
    if (node < N_NODES) rowptr[node] = base + ex;
    if (b == NB - 1 && tid == 0) rowptr[N_NODES] = N_EDGES;
    __syncthreads();
    cnt[tid] = ex;                     // local cursor
    __syncthreads();
    for (int i = tid; i < cntE; i += 256) {
        int p = inLds ? ebuf[i] : pairbuf[base + i];
        int pos = atomicAdd(&cnt[(p >> 17) & 255], 1);
        csr[base + pos] = p & 0x1FFFF;
    }
}

// ---------------------------------------------------------------------------
// K1: t1 = half(x @ W1_nbr) ; r1 = x @ W1_root + b1      (128 -> 16 each)
// ---------------------------------------------------------------------------
__global__ __launch_bounds__(256) void k_transform1(
    const float* __restrict__ x,
    const float* __restrict__ W1n, const float* __restrict__ W1r,
    const float* __restrict__ b1,
    __half* __restrict__ t1, float* __restrict__ r1)
{
    __shared__ float sW[IN_CH * 32];   // [k][c]  c<16: nbr, c>=16: root
    __shared__ float sx[8 * IN_CH];

    for (int i = threadIdx.x; i < IN_CH * 32; i += 256) {
        int k = i >> 5, c = i & 31;
        sW[i] = (c < 16) ? W1n[k * 16 + c] : W1r[k * 16 + (c - 16)];
    }
    int node0 = blockIdx.x * 8;
    ((float4*)sx)[threadIdx.x] = ((const float4*)(x + (long)node0 * IN_CH))[threadIdx.x];
    __syncthreads();

    int c  = threadIdx.x & 31;
    int nl = threadIdx.x >> 5;
    const float* xr = &sx[nl * IN_CH];
    float acc = 0.f;
#pragma unroll 8
    for (int k = 0; k < IN_CH; ++k) acc += xr[k] * sW[k * 32 + c];

    int node = node0 + nl;
    if (c < 16) t1[node * 16 + c] = __float2half_rn(acc);
    else        r1[node * 16 + (c - 16)] = acc + b1[c - 16];
}

// ---------------------------------------------------------------------------
// Gather (CSR, fp16 messages, fp32 accumulate). half2 lane mapping:
// gather16: 8 lanes/node (channel pairs), gather32: 16 lanes/node.
// csr loads nontemporal (streamed once) so they don't evict t from L2.
// ---------------------------------------------------------------------------
__global__ __launch_bounds__(256) void k_gather16(
    const int* __restrict__ rowptr, const int* __restrict__ csr,
    const __half2* __restrict__ t, float2* __restrict__ agg)
{
    int tid = blockIdx.x * 256 + threadIdx.x;      // exactly N_NODES*8 threads
    int n = tid >> 3, cp = tid & 7;
    int j = rowptr[n], end = rowptr[n + 1];
    float2 a0 = {0.f, 0.f}, a1 = {0.f, 0.f}, a2 = {0.f, 0.f}, a3 = {0.f, 0.f};
    for (; j + 7 < end; j += 8) {
        int s0 = __builtin_nontemporal_load(&csr[j]);
        int s1 = __builtin_nontemporal_load(&csr[j + 1]);
        int s2 = __builtin_nontemporal_load(&csr[j + 2]);
        int s3 = __builtin_nontemporal_load(&csr[j + 3]);
        int s4 = __builtin_nontemporal_load(&csr[j + 4]);
        int s5 = __builtin_nontemporal_load(&csr[j + 5]);
        int s6 = __builtin_nontemporal_load(&csr[j + 6]);
        int s7 = __builtin_nontemporal_load(&csr[j + 7]);
        float2 f0 = __half22float2(t[s0 * 8 + cp]);
        float2 f1 = __half22float2(t[s1 * 8 + cp]);
        float2 f2 = __half22float2(t[s2 * 8 + cp]);
        float2 f3 = __half22float2(t[s3 * 8 + cp]);
        float2 f4 = __half22float2(t[s4 * 8 + cp]);
        float2 f5 = __half22float2(t[s5 * 8 + cp]);
        float2 f6 = __half22float2(t[s6 * 8 + cp]);
        float2 f7 = __half22float2(t[s7 * 8 + cp]);
        a0.x += f0.x; a0.y += f0.y;  a1.x += f1.x; a1.y += f1.y;
        a2.x += f2.x; a2.y += f2.y;  a3.x += f3.x; a3.y += f3.y;
        a0.x += f4.x; a0.y += f4.y;  a1.x += f5.x; a1.y += f5.y;
        a2.x += f6.x; a2.y += f6.y;  a3.x += f7.x; a3.y += f7.y;
    }
    for (; j < end; ++j) {
        float2 f = __half22float2(t[__builtin_nontemporal_load(&csr[j]) * 8 + cp]);
        a0.x += f.x; a0.y += f.y;
    }
    float2 r;
    r.x = (a0.x + a1.x) + (a2.x + a3.x);
    r.y = (a0.y + a1.y) + (a2.y + a3.y);
    agg[n * 8 + cp] = r;
}

__global__ __launch_bounds__(256) void k_gather32(
    const int* __restrict__ rowptr, const int* __restrict__ csr,
    const __half2* __restrict__ t, float2* __restrict__ agg)
{
    int tid = blockIdx.x * 256 + threadIdx.x;      // exactly N_NODES*16 threads
    int n = tid >> 4, cp = tid & 15;
    int j = rowptr[n], end = rowptr[n + 1];
    float2 a0 = {0.f, 0.f}, a1 = {0.f, 0.f}, a2 = {0.f, 0.f}, a3 = {0.f, 0.f};
    for (; j + 7 < end; j += 8) {
        int s0 = __builtin_nontemporal_load(&csr[j]);
        int s1 = __builtin_nontemporal_load(&csr[j + 1]);
        int s2 = __builtin_nontemporal_load(&csr[j + 2]);
        int s3 = __builtin_nontemporal_load(&csr[j + 3]);
        int s4 = __builtin_nontemporal_load(&csr[j + 4]);
        int s5 = __builtin_nontemporal_load(&csr[j + 5]);
        int s6 = __builtin_nontemporal_load(&csr[j + 6]);
        int s7 = __builtin_nontemporal_load(&csr[j + 7]);
        float2 f0 = __half22float2(t[s0 * 16 + cp]);
        float2 f1 = __half22float2(t[s1 * 16 + cp]);
        float2 f2 = __half22float2(t[s2 * 16 + cp]);
        float2 f3 = __half22float2(t[s3 * 16 + cp]);
        float2 f4 = __half22float2(t[s4 * 16 + cp]);
        float2 f5 = __half22float2(t[s5 * 16 + cp]);
        float2 f6 = __half22float2(t[s6 * 16 + cp]);
        float2 f7 = __half22float2(t[s7 * 16 + cp]);
        a0.x += f0.x; a0.y += f0.y;  a1.x += f1.x; a1.y += f1.y;
        a2.x += f2.x; a2.y += f2.y;  a3.x += f3.x; a3.y += f3.y;
        a0.x += f4.x; a0.y += f4.y;  a1.x += f5.x; a1.y += f5.y;
        a2.x += f6.x; a2.y += f6.y;  a3.x += f7.x; a3.y += f7.y;
    }
    for (; j < end; ++j) {
        float2 f = __half22float2(t[__builtin_nontemporal_load(&csr[j]) * 16 + cp]);
        a0.x += f.x; a0.y += f.y;
    }
    float2 r;
    r.x = (a0.x + a1.x) + (a2.x + a3.x);
    r.y = (a0.y + a1.y) + (a2.y + a3.y);
    agg[n * 16 + cp] = r;
}

// ---------------------------------------------------------------------------
// K3: h1 = relu(r1 + agg); t2 = half(h1 @ W2_nbr); r2 = h1 @ W2_root + b2
// ---------------------------------------------------------------------------
__global__ __launch_bounds__(256) void k_combine1_transform2(
    const float* __restrict__ r1, const float* __restrict__ agg1,
    const float* __restrict__ W2n, const float* __restrict__ W2r,
    const float* __restrict__ b2,
    __half* __restrict__ t2, float* __restrict__ r2)
{
    __shared__ float sW[16 * 64];   // [k][c]
    __shared__ float sh[4 * 16];

    for (int i = threadIdx.x; i < 16 * 64; i += 256) {
        int k = i >> 6, c = i & 63;
        sW[i] = (c < 32) ? W2n[k * 32 + c] : W2r[k * 32 + (c - 32)];
    }
    int node0 = blockIdx.x * 4;
    if (threadIdx.x < 64) {
        int idx = node0 * 16 + threadIdx.x;
        float v = r1[idx] + agg1[idx];
        sh[threadIdx.x] = v > 0.f ? v : 0.f;
    }
    __syncthreads();

    int c  = threadIdx.x & 63;
    int nl = threadIdx.x >> 6;
    const float* hr = &sh[nl * 16];
    float acc = 0.f;
#pragma unroll
    for (int k = 0; k < 16; ++k) acc += hr[k] * sW[k * 64 + c];

    int node = node0 + nl;
    if (c < 32) t2[node * 32 + c] = __float2half_rn(acc);
    else        r2[node * 32 + (c - 32)] = acc + b2[c - 32];
}

// ---------------------------------------------------------------------------
// K5: h2 = relu(r2 + agg); t3 = half(h2 @ W3_nbr); r3 = h2 @ W3_root + b3
// t3/r3 alias t2/r2 — block reads its slice first, barrier, overwrites.
// ---------------------------------------------------------------------------
__global__ __launch_bounds__(256) void k_combine2_transform3(
    const float* __restrict__ r2, const float* __restrict__ agg2,
    const float* __restrict__ W3n, const float* __restrict__ W3r,
    const float* __restrict__ b3,
    __half* __restrict__ t3, float* __restrict__ r3)
{
    __shared__ float sW[32 * 64];
    __shared__ float sh[4 * 32];

    for (int i = threadIdx.x; i < 32 * 64; i += 256) {
        int k = i >> 6, c = i & 63;
        sW[i] = (c < 32) ? W3n[k * 32 + c] : W3r[k * 32 + (c - 32)];
    }
    int node0 = blockIdx.x * 4;
    if (threadIdx.x < 128) {
        int idx = node0 * 32 + threadIdx.x;
        float v = r2[idx] + agg2[idx];
        sh[threadIdx.x] = v > 0.f ? v : 0.f;
    }
    __syncthreads();

    int c  = threadIdx.x & 63;
    int nl = threadIdx.x >> 6;
    const float* hr = &sh[nl * 32];
    float acc = 0.f;
#pragma unroll
    for (int k = 0; k < 32; ++k) acc += hr[k] * sW[k * 64 + c];

    int node = node0 + nl;
    if (c < 32) t3[node * 32 + c] = __float2half_rn(acc);
    else        r3[node * 32 + (c - 32)] = acc + b3[c - 32];
}

// ---------------------------------------------------------------------------
// K7: h3 = relu(r3 + agg); pooled[batch[n]] += h3[n]
// ---------------------------------------------------------------------------
__global__ __launch_bounds__(256) void k_combine3_pool(
    const float* __restrict__ r3, const float* __restrict__ agg3,
    const int* __restrict__ batch, float* __restrict__ pooled)
{
    int tid = blockIdx.x * 256 + threadIdx.x;
    if (tid >= N_NODES * 32) return;
    int n = tid >> 5, c = tid & 31;
    float v = r3[tid] + agg3[tid];
    v = v > 0.f ? v : 0.f;
    atomicAdd(&pooled[batch[n] * 32 + c], v);
}

// ---------------------------------------------------------------------------
// K8: out = pooled @ Wlin + blin   (1000x32 @ 32x64)
// ---------------------------------------------------------------------------
__global__ __launch_bounds__(64) void k_final(
    const float* __restrict__ pooled, const float* __restrict__ Wlin,
    const float* __restrict__ blin, float* __restrict__ out)
{
    int g = blockIdx.x;
    int o = threadIdx.x;
    float acc = blin[o];
#pragma unroll
    for (int k = 0; k < 32; ++k) acc += pooled[g * 32 + k] * Wlin[k * 64 + o];
    out[g * 64 + o] = acc;
}

static inline char* align16(char* p) {
    return (char*)(((uintptr_t)p + 15) & ~(uintptr_t)15);
}

extern "C" void kernel_launch(void* const* d_in, const int* in_sizes, int n_in,
                              void* d_out, int out_size, void* d_ws, size_t ws_size,
                              hipStream_t stream) {
    const float* x     = (const float*)d_in[0];
    const int*   ei    = (const int*)d_in[1];
    const int*   batch = (const int*)d_in[2];
    const float* W1r   = (const float*)d_in[3];
    const float* W1n   = (const float*)d_in[4];
    const float* b1    = (const float*)d_in[5];
    const float* W2r   = (const float*)d_in[6];
    const float* W2n   = (const float*)d_in[7];
    const float* b2    = (const float*)d_in[8];
    const float* W3r   = (const float*)d_in[9];
    const float* W3n   = (const float*)d_in[10];
    const float* b3    = (const float*)d_in[11];
    const float* Wlin  = (const float*)d_in[12];
    const float* blin  = (const float*)d_in[13];
    float* out = (float*)d_out;

    // ---- workspace layout --------------------------------------------------
    // zero region: gcount[512] + pooled[32000 floats]       (one small memset)
    // boff[512] cursor[512] rowptr[100001] csr[3.2M ints]
    // pairbuf[3.2M ints, 12.8MB]  -- aliases t1(half,3.2MB)+r1(f32,6.4MB)
    // t2 half 6.4MB, r2 f32 12.8MB, agg f32 12.8MB; t3/r3 alias t2/r2.
    char* p = (char*)d_ws;
    int*   gcount = (int*)p;               p += 512 * 4;
    float* pooled = (float*)p;             p += (size_t)NUM_GRAPHS * 32 * 4;
    int*   boff   = (int*)p;               p += 512 * 4;
    int*   cursor = (int*)p;               p += 512 * 4;
    int*   rowptr = (int*)p;               p = align16(p + (N_NODES + 1) * 4);
    int*   csr    = (int*)p;               p += (size_t)N_EDGES * 4;
    int*   pairbuf= (int*)p;
    __half* t1    = (__half*)pairbuf;                                  // alias
    float*  r1    = (float*)((char*)pairbuf + (size_t)N_NODES * 16 * 2);
    p += (size_t)N_EDGES * 4;
    __half* t2    = (__half*)p;            p += (size_t)N_NODES * 32 * 2;
    float*  r2    = (float*)p;             p += (size_t)N_NODES * 32 * 4;
    float*  agg   = (float*)p;
    __half* t3    = t2;   // in-place
    float*  r3    = r2;   // in-place

    hipMemsetAsync(gcount, 0, (512 + (size_t)NUM_GRAPHS * 32) * 4, stream);

    // CSR build (bucketed, write-allocate-friendly)
    k_count_buckets<<<NBLK_BIN, 256, 0, stream>>>(ei, gcount);
    k_scan_buckets <<<1, 512, 0, stream>>>(gcount, boff, cursor);
    k_scatter_pairs<<<NBLK_BIN, 256, 0, stream>>>(ei, cursor, pairbuf);
    k_build_csr    <<<NB, 256, 0, stream>>>(gcount, boff, pairbuf, rowptr, csr);

    // Layer pipeline
    k_transform1<<<N_NODES / 8, 256, 0, stream>>>(x, W1n, W1r, b1, t1, r1);
    k_gather16  <<<N_NODES * 8 / 256, 256, 0, stream>>>(rowptr, csr,
                    (const __half2*)t1, (float2*)agg);
    k_combine1_transform2<<<N_NODES / 4, 256, 0, stream>>>(r1, agg, W2n, W2r, b2, t2, r2);
    k_gather32  <<<N_NODES * 16 / 256, 256, 0, stream>>>(rowptr, csr,
                    (const __half2*)t2, (float2*)agg);
    k_combine2_transform3<<<N_NODES / 4, 256, 0, stream>>>(r2, agg, W3n, W3r, b3, t3, r3);
    k_gather32  <<<N_NODES * 16 / 256, 256, 0, stream>>>(rowptr, csr,
                    (const __half2*)t3, (float2*)agg);
    k_combine3_pool<<<N_NODES * 32 / 256, 256, 0, stream>>>(r3, agg, batch, pooled);
    k_final     <<<NUM_GRAPHS, 64, 0, stream>>>(pooled, Wlin, blin, out);
}